// Round 8
// baseline (32.492 us; speedup 1.0000x reference)
//
#include <hip/hip_runtime.h>
#include <math.h>
#include <stdint.h>

// Problem dims (fixed by reference setup_inputs)
#define BB 4
#define CC 8
#define PP 20
#define AA 30
#define SS 4
#define TT 2048
#define NB 18

#define TC 128                  // t-chunk (K-slab) per iteration
#define NCH (TT / TC)           // 16 chunks
#define PG 4                    // p's per block = waves per block
#define NPG (PP / PG)           // 5 p-groups
#define WSTR 132                // f16 row stride: 264 B -> bank step 2 (2-way free), 8B-aligned
#define WROWS 19                // rows 0..17 = W, row 18 = dump row for the unwrapped edge
#define NTH 256                 // 4 waves; wave w owns p = pg*4 + w

// Relaxed barrier: LDS-visibility only; global loads stay in flight across it.
#define BAR() do { asm volatile("s_waitcnt lgkmcnt(0)" ::: "memory"); \
                   __builtin_amdgcn_s_barrier(); } while (0)

typedef _Float16 half4_t __attribute__((ext_vector_type(4)));
typedef _Float16 half8_t __attribute__((ext_vector_type(8)));
typedef float f32x16 __attribute__((ext_vector_type(16)));

__device__ __forceinline__ void weight_top2(float x, int& n0, int& n1,
                                            float& w0, float& w1)
{
    const float PI_F  = 3.14159265358979323846f;
    const float INV_H = 2.8647913f;           // 18 / (2*pi)
    float u = (x + PI_F) * INV_H;             // in [0, 18]
    n0 = (int)floorf(u);
    n0 = n0 < 0 ? 0 : (n0 > NB - 1 ? NB - 1 : n0);
    float f  = u - (float)n0 - 0.5f;          // [-0.5, 0.5]
    float af = fabsf(f);
    n1 = n0 + (f >= 0.0f ? 1 : -1);
    float e;
    if (n1 < 0) {                             // reference's unwrapped low edge: w1 ~ 7e-16
        e = 0.0f; n1 = NB;                    // row 18 gets 0.0 (never extracted)
    } else {
        if (n1 == NB) n1 = 0;                 // positive wrap: same gap formula
        // exp(-(H*(1-2af))*100) = exp(69.81317*af - 34.906585), folded
        e = __expf(fmaf(af, 69.81317008f, -34.90658504f));
    }
    w0 = __builtin_amdgcn_rcpf(1.0f + e);     // rel err ~1e-7 << f16 quantization
    w1 = 1.0f - w0;
}

// ---------------------------------------------------------------------------
// Single fused kernel. Block = (bc, s, pgroup); wave w owns p = pg*4+w fully
// (wave-private W scatter, register K-accumulation, wave-local epilogue).
// Shared state = double-buffered ampT -> ONE relaxed barrier per chunk.
// 2-DEEP amp staging: chunk c+2 issued at iter c, written to LDS at iter c+1,
// consumed at iter c+2 -> a full iteration of latency slack per load.
// XCD swizzle: the 5 blocks sharing an amp slice map to the SAME XCD.
// ---------------------------------------------------------------------------
__global__ __launch_bounds__(NTH, 4)
void mi_fused_kernel(const float* __restrict__ phase,
                     const float* __restrict__ amp,
                     float* __restrict__ out)
{
    __shared__ _Float16 Wl[4][WROWS * WSTR];   // 4 x 5,016 B, wave-private tiles
    __shared__ _Float16 ampT[2][AA * WSTR];    // 2 x 7,920 B, double-buffered

    const int tid = threadIdx.x;
    // ---- XCD-aware swizzle (bijective 640->640): sharing group g stays on xcd x
    const int bid = blockIdx.x;
    const int x   = bid & 7;                   // physical XCD (dispatch model)
    const int kk  = bid >> 3;                  // 0..79
    const int pg  = kk % NPG;                  // member within amp-sharing group
    const int g   = x + 8 * (kk / NPG);        // 0..127 = bc*SS + s
    const int s   = g & (SS - 1);
    const int bc  = g >> 2;                    // b*CC + c

    const int wv   = tid >> 6;
    const int lane = tid & 63;
    const int mrow = lane & 31;
    const int mlh  = lane >> 5;
    const int arow = mrow < WROWS ? mrow : (WROWS - 1);  // A rows >=19 -> zero row 18
    const int brow = mrow < AA    ? mrow : (AA - 1);     // B rows 30,31 -> dup (unused cols)

    const int p = pg * PG + wv;                // this wave's p
    const float* am  = amp   + (size_t)bc * (AA * SS * TT) + (size_t)s * TT;
    const float* phw = phase + ((size_t)(bc * PP + p) * SS + s) * TT;
    float*       op  = out   + ((size_t)(bc * SS + s) * PP + p) * AA;

    // ---- prologue: zero own W tile, stage chunk 0, issue chunk 1 -> stgA ----
    {
        uint2* wz = (uint2*)&Wl[wv][0];        // 5,016 B = 627 uint2
        for (int i = lane; i < 627; i += 64) wz[i] = make_uint2(0u, 0u);
    }
    #pragma unroll
    for (int j = 0; j < 4; ++j) {              // stage chunk 0: 960 quads, coop
        int q = tid + j * 256;
        int a = q >> 5, tq = q & 31;           // 32 quads per row (TC/4)
        if (a < AA) {
            const float4 v = *(const float4*)&am[(size_t)a * (SS * TT) + tq * 4];
            half4_t h = { (_Float16)v.x, (_Float16)v.y, (_Float16)v.z, (_Float16)v.w };
            *(half4_t*)&ampT[0][a * WSTR + tq * 4] = h;
        }
    }
    float4 stgA[4], stgB[4];
    #pragma unroll
    for (int j = 0; j < 4; ++j) {              // issue chunk 1 -> stgA
        int q = tid + j * 256;
        int a = q >> 5, tq = q & 31;
        int ac = a < AA ? a : (AA - 1);
        stgA[j] = *(const float4*)&am[(size_t)ac * (SS * TT) + TC + tq * 4];
    }
    float2 ph2 = *(const float2*)&phw[lane * 2];
    BAR();

    f32x16 acc0 = {}, acc1 = {};
    int pn0[2], pn1[2];

    // One pipeline step: at iter C, issue chunk C+2 -> SOUT, write SIN
    // (holding chunk C+1, issued at iter C-1) -> ampT[(C+1)&1], then
    // weights+scatter, 8 MFMA on ampT[C&1], relaxed BAR.
    #define STEP(C, SIN, SOUT)                                                 \
    {                                                                          \
        if ((C) + 2 < NCH) {                                                   \
            _Pragma("unroll")                                                  \
            for (int j = 0; j < 4; ++j) {                                      \
                int q = tid + j * 256;                                         \
                int a = q >> 5, tq = q & 31;                                   \
                int ac = a < AA ? a : (AA - 1);                                \
                SOUT[j] = *(const float4*)&am[(size_t)ac * (SS * TT)           \
                                              + ((C) + 2) * TC + tq * 4];      \
            }                                                                  \
        }                                                                      \
        float2 nph2 = {};                                                      \
        if ((C) + 1 < NCH)                                                     \
            nph2 = *(const float2*)&phw[((C) + 1) * TC + lane * 2];            \
        if ((C) + 1 < NCH) {   /* write arrived chunk C+1 to other buffer */   \
            _Pragma("unroll")                                                  \
            for (int j = 0; j < 4; ++j) {                                      \
                int q = tid + j * 256;                                         \
                int a = q >> 5, tq = q & 31;                                   \
                if (a < AA) {                                                  \
                    half4_t h = { (_Float16)SIN[j].x, (_Float16)SIN[j].y,      \
                                  (_Float16)SIN[j].z, (_Float16)SIN[j].w };    \
                    *(half4_t*)&ampT[((C) + 1) & 1][a * WSTR + tq * 4] = h;    \
                }                                                              \
            }                                                                  \
        }                                                                      \
        _Pragma("unroll")                                                      \
        for (int j = 0; j < 2; ++j) {                                          \
            int col = lane * 2 + j;                                            \
            if ((C) > 0) {                                                     \
                Wl[wv][pn0[j] * WSTR + col] = (_Float16)0.0f;                  \
                Wl[wv][pn1[j] * WSTR + col] = (_Float16)0.0f;                  \
            }                                                                  \
            int n0, n1; float w0, w1;                                          \
            weight_top2(j == 0 ? ph2.x : ph2.y, n0, n1, w0, w1);               \
            Wl[wv][n0 * WSTR + col] = (_Float16)w0;                            \
            Wl[wv][n1 * WSTR + col] = (_Float16)w1;                            \
            pn0[j] = n0; pn1[j] = n1;                                          \
        }                                                                      \
        _Pragma("unroll")                                                      \
        for (int ks = 0; ks < 8; ++ks) {                                       \
            int t0 = ks * 16 + mlh * 8;                                        \
            const _Float16* Ab = &Wl[wv][arow * WSTR + t0];                    \
            const _Float16* Bb = &ampT[(C) & 1][brow * WSTR + t0];             \
            half4_t a0 = *(const half4_t*)Ab;                                  \
            half4_t a1 = *(const half4_t*)(Ab + 4);                            \
            half4_t b0 = *(const half4_t*)Bb;                                  \
            half4_t b1 = *(const half4_t*)(Bb + 4);                            \
            half8_t av = __builtin_shufflevector(a0, a1, 0, 1, 2, 3, 4, 5, 6, 7); \
            half8_t bv = __builtin_shufflevector(b0, b1, 0, 1, 2, 3, 4, 5, 6, 7); \
            if (ks & 1) acc1 = __builtin_amdgcn_mfma_f32_32x32x16_f16(av, bv, acc1, 0, 0, 0); \
            else        acc0 = __builtin_amdgcn_mfma_f32_32x32x16_f16(av, bv, acc0, 0, 0, 0); \
        }                                                                      \
        ph2 = nph2;                                                            \
        BAR();                                                                 \
    }

    #pragma unroll 1
    for (int c = 0; c < NCH; c += 2) {         // NCH even: static stgA/stgB swap
        STEP(c,     stgA, stgB);
        STEP(c + 1, stgB, stgA);
    }
    #undef STEP

    // ---- epilogue (wave-local): dump acc, entropy, store ----
    f32x16 acc = acc0 + acc1;
    float* dmp = (float*)&Wl[wv][0];           // own tile dead; [18][33] f32 fits
    #pragma unroll
    for (int r = 0; r < 16; ++r) {
        int row = (r & 3) + 8 * (r >> 2) + 4 * mlh;   // HW-verified C/D layout
        if (row < NB) dmp[row * 33 + mrow] = acc[r];
    }
    // wave64-coherent LDS: in-order ds pipe + compiler lgkmcnt; no barrier needed
    if (lane < AA) {
        float v[NB], tot = 0.0f;
        #pragma unroll
        for (int n = 0; n < NB; ++n) { v[n] = dmp[n * 33 + lane]; tot += v[n]; }
        float inv = 1.0f / (tot + 1e-10f);
        float ne = 0.0f;
        #pragma unroll
        for (int n = 0; n < NB; ++n) {
            float pv = fmaxf(v[n] * inv, 1e-10f);
            ne += pv * logf(pv);
        }
        op[lane] = 1.0f + ne * 0.345975362f;   // 1/log(18)
    }
}

extern "C" void kernel_launch(void* const* d_in, const int* in_sizes, int n_in,
                              void* d_out, int out_size, void* d_ws, size_t ws_size,
                              hipStream_t stream)
{
    const float* phase = (const float*)d_in[0];
    const float* amp   = (const float*)d_in[1];
    float* out = (float*)d_out;
    hipLaunchKernelGGL(mi_fused_kernel, dim3(BB * CC * SS * NPG), dim3(NTH),
                       0, stream, phase, amp, out);
}

// Round 9
// 30.585 us; speedup vs baseline: 1.0623x; 1.0623x over previous
//
#include <hip/hip_runtime.h>
#include <math.h>
#include <stdint.h>

// Problem dims (fixed by reference setup_inputs)
#define BB 4
#define CC 8
#define PP 20
#define AA 30
#define SS 4
#define TT 2048
#define NB 18

#define TC 128                  // t-chunk (K-slab) per iteration
#define NCH (TT / TC)           // 16 chunks
#define PG 2                    // p's per block = waves per block
#define NPG (PP / PG)           // 10 p-groups
#define WSTR 132                // f16 row stride: 264 B -> bank step 2 (2-way free), 8B-aligned
#define WROWS 19                // rows 0..17 = W, row 18 = dump row for the unwrapped edge
#define NTH 128                 // 2 waves; wave w owns p = pg*2 + w

// Relaxed barrier: LDS-visibility only; global loads stay in flight across it.
#define BAR() do { asm volatile("s_waitcnt lgkmcnt(0)" ::: "memory"); \
                   __builtin_amdgcn_s_barrier(); } while (0)

typedef _Float16 half4_t __attribute__((ext_vector_type(4)));
typedef _Float16 half8_t __attribute__((ext_vector_type(8)));
typedef float f32x16 __attribute__((ext_vector_type(16)));

__device__ __forceinline__ void weight_top2(float x, int& n0, int& n1,
                                            float& w0, float& w1)
{
    const float PI_F  = 3.14159265358979323846f;
    const float INV_H = 2.8647913f;           // 18 / (2*pi)
    float u = (x + PI_F) * INV_H;             // in [0, 18]
    n0 = (int)floorf(u);
    n0 = n0 < 0 ? 0 : (n0 > NB - 1 ? NB - 1 : n0);
    float f  = u - (float)n0 - 0.5f;          // [-0.5, 0.5]
    float af = fabsf(f);
    n1 = n0 + (f >= 0.0f ? 1 : -1);
    float e;
    if (n1 < 0) {                             // reference's unwrapped low edge: w1 ~ 7e-16
        e = 0.0f; n1 = NB;                    // row 18 gets 0.0 (never extracted)
    } else {
        if (n1 == NB) n1 = 0;                 // positive wrap: same gap formula
        // exp(-(H*(1-2af))*100) = exp(69.81317*af - 34.906585), folded
        e = __expf(fmaf(af, 69.81317008f, -34.90658504f));
    }
    w0 = __builtin_amdgcn_rcpf(1.0f + e);     // rel err ~1e-7 << f16 quantization
    w1 = 1.0f - w0;
}

// ---------------------------------------------------------------------------
// Single fused kernel (round-7 structure, rebalanced). Block = (bc, s, pg);
// wave w owns p = pg*2+w fully: wave-private W scatter, register K-accum,
// wave-local epilogue. Shared state = double-buffered ampT -> ONE relaxed
// barrier per chunk; issue-early/write-late 1-deep amp staging.
// PG=2/NTH=128: 25.9 KB LDS, grid 1280 = EXACTLY 5 blocks/CU, no imbalance.
// XCD swizzle: the 10 blocks sharing an amp slice map to the SAME XCD.
// ---------------------------------------------------------------------------
__global__ __launch_bounds__(NTH)
void mi_fused_kernel(const float* __restrict__ phase,
                     const float* __restrict__ amp,
                     float* __restrict__ out)
{
    __shared__ _Float16 Wl[PG][WROWS * WSTR];  // 2 x 5,016 B, wave-private tiles
    __shared__ _Float16 ampT[2][AA * WSTR];    // 2 x 7,920 B, double-buffered

    const int tid = threadIdx.x;
    // ---- XCD-aware swizzle (bijective 1280->1280): sharers of one amp slice
    //      land on one XCD (physical XCD ~ blockIdx%8 round-robin dispatch)
    const int bid = blockIdx.x;
    const int x   = bid & 7;                   // physical XCD
    const int kk  = bid >> 3;                  // 0..159
    const int pg  = kk % NPG;                  // member within amp-sharing group
    const int g   = x + 8 * (kk / NPG);        // 0..127 = bc*SS + s
    const int s   = g & (SS - 1);
    const int bc  = g >> 2;                    // b*CC + c

    const int wv   = tid >> 6;                 // 0..1
    const int lane = tid & 63;
    const int mrow = lane & 31;
    const int mlh  = lane >> 5;
    const int arow = mrow < WROWS ? mrow : (WROWS - 1);  // A rows >=19 -> zero row 18
    const int brow = mrow < AA    ? mrow : (AA - 1);     // B rows 30,31 -> dup (unused cols)

    const int p = pg * PG + wv;                // this wave's p
    const float* am  = amp   + (size_t)bc * (AA * SS * TT) + (size_t)s * TT;
    const float* phw = phase + ((size_t)(bc * PP + p) * SS + s) * TT;
    float*       op  = out   + ((size_t)(bc * SS + s) * PP + p) * AA;

    // ---- prologue: zero own W tile, stage chunk 0, load own phase f2 ----
    {
        uint2* wz = (uint2*)&Wl[wv][0];        // 5,016 B = 627 uint2
        for (int i = lane; i < 627; i += 64) wz[i] = make_uint2(0u, 0u);
    }
    #pragma unroll
    for (int j = 0; j < 8; ++j) {              // stage chunk 0: 960 quads, coop
        int q = tid + j * NTH;
        int a = q >> 5, tq = q & 31;           // 32 quads per row (TC/4)
        if (a < AA) {
            const float4 v = *(const float4*)&am[(size_t)a * (SS * TT) + tq * 4];
            half4_t h = { (_Float16)v.x, (_Float16)v.y, (_Float16)v.z, (_Float16)v.w };
            *(half4_t*)&ampT[0][a * WSTR + tq * 4] = h;
        }
    }
    float2 ph2 = *(const float2*)&phw[lane * 2];
    BAR();

    f32x16 acc0 = {}, acc1 = {};
    int pn0[2], pn1[2];

    for (int c = 0; c < NCH; ++c) {
        const int cb = c & 1, tb = cb ^ 1;

        // ---- issue next-chunk global loads EARLY (consumed after MFMA) ----
        float2 nph2 = {};
        float4 stg[8];
        if (c + 1 < NCH) {
            nph2 = *(const float2*)&phw[(c + 1) * TC + lane * 2];
            #pragma unroll
            for (int j = 0; j < 8; ++j) {
                int q = tid + j * NTH;
                int a = q >> 5, tq = q & 31;
                int ac = a < AA ? a : (AA - 1);          // clamp: no OOB read
                stg[j] = *(const float4*)&am[(size_t)ac * (SS * TT) + (c + 1) * TC + tq * 4];
            }
        }

        // ---- unwrite previous chunk's entries, scatter this chunk's ----
        #pragma unroll
        for (int j = 0; j < 2; ++j) {
            int col = lane * 2 + j;
            if (c > 0) {
                Wl[wv][pn0[j] * WSTR + col] = (_Float16)0.0f;
                Wl[wv][pn1[j] * WSTR + col] = (_Float16)0.0f;
            }
            int n0, n1; float w0, w1;
            weight_top2(j == 0 ? ph2.x : ph2.y, n0, n1, w0, w1);
            Wl[wv][n0 * WSTR + col] = (_Float16)w0;
            Wl[wv][n1 * WSTR + col] = (_Float16)w1;
            pn0[j] = n0; pn1[j] = n1;
        }

        // ---- 8 MFMA K-steps (wave-local; ds order makes scatter visible) ----
        __builtin_amdgcn_s_setprio(1);         // prefer MFMA-phase waves on SIMD
        #pragma unroll
        for (int ks = 0; ks < 8; ++ks) {
            int t0 = ks * 16 + mlh * 8;
            const _Float16* Ab = &Wl[wv][arow * WSTR + t0];
            const _Float16* Bb = &ampT[cb][brow * WSTR + t0];
            half4_t a0 = *(const half4_t*)Ab;
            half4_t a1 = *(const half4_t*)(Ab + 4);
            half4_t b0 = *(const half4_t*)Bb;
            half4_t b1 = *(const half4_t*)(Bb + 4);
            half8_t av = __builtin_shufflevector(a0, a1, 0, 1, 2, 3, 4, 5, 6, 7);
            half8_t bv = __builtin_shufflevector(b0, b1, 0, 1, 2, 3, 4, 5, 6, 7);
            if (ks & 1) acc1 = __builtin_amdgcn_mfma_f32_32x32x16_f16(av, bv, acc1, 0, 0, 0);
            else        acc0 = __builtin_amdgcn_mfma_f32_32x32x16_f16(av, bv, acc0, 0, 0, 0);
        }
        __builtin_amdgcn_s_setprio(0);

        // ---- write-late: stage next chunk into the other buffer ----
        if (c + 1 < NCH) {
            #pragma unroll
            for (int j = 0; j < 8; ++j) {
                int q = tid + j * NTH;
                int a = q >> 5, tq = q & 31;
                if (a < AA) {
                    half4_t h = { (_Float16)stg[j].x, (_Float16)stg[j].y,
                                  (_Float16)stg[j].z, (_Float16)stg[j].w };
                    *(half4_t*)&ampT[tb][a * WSTR + tq * 4] = h;
                }
            }
        }
        ph2 = nph2;
        BAR();   // syncs ampT only: my reads of [cb] done; my writes to [tb] visible
    }

    // ---- epilogue (wave-local): dump acc, entropy, store ----
    f32x16 acc = acc0 + acc1;
    float* dmp = (float*)&Wl[wv][0];           // own tile dead; [18][33] f32 fits
    #pragma unroll
    for (int r = 0; r < 16; ++r) {
        int row = (r & 3) + 8 * (r >> 2) + 4 * mlh;   // HW-verified C/D layout
        if (row < NB) dmp[row * 33 + mrow] = acc[r];
    }
    // wave64-coherent LDS: in-order ds pipe + compiler lgkmcnt; no barrier needed
    if (lane < AA) {
        float v[NB], tot = 0.0f;
        #pragma unroll
        for (int n = 0; n < NB; ++n) { v[n] = dmp[n * 33 + lane]; tot += v[n]; }
        float inv = 1.0f / (tot + 1e-10f);
        float ne = 0.0f;
        #pragma unroll
        for (int n = 0; n < NB; ++n) {
            float pv = fmaxf(v[n] * inv, 1e-10f);
            ne += pv * logf(pv);
        }
        op[lane] = 1.0f + ne * 0.345975362f;   // 1/log(18)
    }
}

extern "C" void kernel_launch(void* const* d_in, const int* in_sizes, int n_in,
                              void* d_out, int out_size, void* d_ws, size_t ws_size,
                              hipStream_t stream)
{
    const float* phase = (const float*)d_in[0];
    const float* amp   = (const float*)d_in[1];
    float* out = (float*)d_out;
    hipLaunchKernelGGL(mi_fused_kernel, dim3(BB * CC * SS * NPG), dim3(NTH),
                       0, stream, phase, amp, out);
}

// Round 10
// 28.997 us; speedup vs baseline: 1.1206x; 1.0548x over previous
//
#include <hip/hip_runtime.h>
#include <math.h>
#include <stdint.h>

// Problem dims (fixed by reference setup_inputs)
#define BB 4
#define CC 8
#define PP 20
#define AA 30
#define SS 4
#define TT 2048
#define NB 18

#define TC 128                  // t-chunk (K-slab) per iteration
#define NCH (TT / TC)           // 16 chunks
#define PG 2                    // p's per block
#define NPG (PP / PG)           // 10 p-groups
#define WSTR 132                // f16 row stride: 264 B -> bank step 2 (2-way free), 8B-aligned
#define WROWS 19                // rows 0..17 = W, row 18 = dump row for the unwrapped edge
#define NTH 256                 // 4 waves = 2 p (wv) x 2 K-halves (kh)

// Relaxed barrier: LDS-visibility only; global loads stay in flight across it.
#define BAR() do { asm volatile("s_waitcnt lgkmcnt(0)" ::: "memory"); \
                   __builtin_amdgcn_s_barrier(); } while (0)

typedef _Float16 half4_t __attribute__((ext_vector_type(4)));
typedef _Float16 half8_t __attribute__((ext_vector_type(8)));
typedef float f32x16 __attribute__((ext_vector_type(16)));

__device__ __forceinline__ void weight_top2(float x, int& n0, int& n1,
                                            float& w0, float& w1)
{
    const float PI_F  = 3.14159265358979323846f;
    const float INV_H = 2.8647913f;           // 18 / (2*pi)
    float u = (x + PI_F) * INV_H;             // in [0, 18]
    n0 = (int)floorf(u);
    n0 = n0 < 0 ? 0 : (n0 > NB - 1 ? NB - 1 : n0);
    float f  = u - (float)n0 - 0.5f;          // [-0.5, 0.5]
    float af = fabsf(f);
    n1 = n0 + (f >= 0.0f ? 1 : -1);
    float e;
    if (n1 < 0) {                             // reference's unwrapped low edge: w1 ~ 7e-16
        e = 0.0f; n1 = NB;                    // row 18 gets 0.0 (never extracted)
    } else {
        if (n1 == NB) n1 = 0;                 // positive wrap: same gap formula
        // exp(-(H*(1-2af))*100) = exp(69.81317*af - 34.906585), folded
        e = __expf(fmaf(af, 69.81317008f, -34.90658504f));
    }
    w0 = __builtin_amdgcn_rcpf(1.0f + e);     // rel err ~1e-7 << f16 quantization
    w1 = 1.0f - w0;
}

// ---------------------------------------------------------------------------
// Single fused kernel, K-split waves. Block = (bc, s, pg); wave (wv, kh)
// owns p = pg*2+wv, t-columns [kh*64, kh*64+64) of the chunk: scatter,
// unwrite, A-reads, MFMA all wave-local (1 t-col/lane). 5120 waves total
// -> 20 waves/CU (5/SIMD), same total work as before: pure parallelism gain.
// Shared state = double-buffered ampT -> ONE relaxed barrier per chunk.
// Epilogue: kh partials merged via dead-W-tile LDS dump + one BAR.
// XCD swizzle: the 10 blocks sharing an amp slice map to the SAME XCD.
// ---------------------------------------------------------------------------
__global__ __launch_bounds__(NTH, 5)
void mi_fused_kernel(const float* __restrict__ phase,
                     const float* __restrict__ amp,
                     float* __restrict__ out)
{
    __shared__ __align__(16) _Float16 Wl[PG][WROWS * WSTR];  // 2 x 5,016 B
    __shared__ __align__(16) _Float16 ampT[2][AA * WSTR];    // 2 x 7,920 B dbuf

    const int tid = threadIdx.x;
    // ---- XCD-aware swizzle (bijective 1280->1280): sharers of one amp slice
    //      land on one XCD (physical XCD ~ blockIdx%8 round-robin dispatch)
    const int bid = blockIdx.x;
    const int x   = bid & 7;                   // physical XCD
    const int kk  = bid >> 3;                  // 0..159
    const int pg  = kk % NPG;                  // member within amp-sharing group
    const int g   = x + 8 * (kk / NPG);        // 0..127 = bc*SS + s
    const int s   = g & (SS - 1);
    const int bc  = g >> 2;                    // b*CC + c

    const int w    = tid >> 6;                 // wave 0..3
    const int wv   = w & 1;                    // p within pair
    const int kh   = w >> 1;                   // K-half of the chunk
    const int lane = tid & 63;
    const int mrow = lane & 31;
    const int mlh  = lane >> 5;
    const int arow = mrow < WROWS ? mrow : (WROWS - 1);  // A rows >=19 -> zero row 18
    const int brow = mrow < AA    ? mrow : (AA - 1);     // B rows 30,31 -> dup (unused cols)
    const int col  = kh * 64 + lane;           // this lane's owned t-column

    const int p = pg * PG + wv;                // this wave's p
    const float* am  = amp   + (size_t)bc * (AA * SS * TT) + (size_t)s * TT;
    const float* phw = phase + ((size_t)(bc * PP + p) * SS + s) * TT;
    float*       op  = out   + ((size_t)(bc * SS + s) * PP + p) * AA;

    // ---- prologue: zero both W tiles, stage chunk 0, load own phase col ----
    for (int i = tid; i < 2 * 627; i += NTH)   // 10,032 B = 1,254 uint2
        ((uint2*)Wl)[i] = make_uint2(0u, 0u);
    #pragma unroll
    for (int j = 0; j < 4; ++j) {              // stage chunk 0: 960 quads, coop
        int q = tid + j * NTH;
        int a = q >> 5, tq = q & 31;           // 32 quads per row (TC/4)
        if (a < AA) {
            const float4 v = *(const float4*)&am[(size_t)a * (SS * TT) + tq * 4];
            half4_t h = { (_Float16)v.x, (_Float16)v.y, (_Float16)v.z, (_Float16)v.w };
            *(half4_t*)&ampT[0][a * WSTR + tq * 4] = h;
        }
    }
    float phv = phw[col];
    BAR();

    f32x16 acc0 = {}, acc1 = {};
    int pn0 = 0, pn1 = 0;

    for (int c = 0; c < NCH; ++c) {
        const int cb = c & 1, tb = cb ^ 1;

        // ---- issue next-chunk global loads EARLY (consumed after MFMA) ----
        float nphv = 0.0f;
        float4 stg[4];
        if (c + 1 < NCH) {
            nphv = phw[(c + 1) * TC + col];
            #pragma unroll
            for (int j = 0; j < 4; ++j) {
                int q = tid + j * NTH;
                int a = q >> 5, tq = q & 31;
                int ac = a < AA ? a : (AA - 1);          // clamp: no OOB read
                stg[j] = *(const float4*)&am[(size_t)ac * (SS * TT) + (c + 1) * TC + tq * 4];
            }
        }

        // ---- unwrite previous chunk's entries, scatter this chunk's ----
        if (c > 0) {
            Wl[wv][pn0 * WSTR + col] = (_Float16)0.0f;
            Wl[wv][pn1 * WSTR + col] = (_Float16)0.0f;
        }
        {
            int n0, n1; float w0, w1;
            weight_top2(phv, n0, n1, w0, w1);
            Wl[wv][n0 * WSTR + col] = (_Float16)w0;
            Wl[wv][n1 * WSTR + col] = (_Float16)w1;
            pn0 = n0; pn1 = n1;
        }

        // ---- 4 MFMA K-steps in this wave's K-half (all wave-local deps) ----
        __builtin_amdgcn_s_setprio(1);         // prefer MFMA-phase waves on SIMD
        #pragma unroll
        for (int ks = 0; ks < 4; ++ks) {
            int t0 = kh * 64 + ks * 16 + mlh * 8;
            const _Float16* Ab = &Wl[wv][arow * WSTR + t0];
            const _Float16* Bb = &ampT[cb][brow * WSTR + t0];
            half4_t a0 = *(const half4_t*)Ab;
            half4_t a1 = *(const half4_t*)(Ab + 4);
            half4_t b0 = *(const half4_t*)Bb;
            half4_t b1 = *(const half4_t*)(Bb + 4);
            half8_t av = __builtin_shufflevector(a0, a1, 0, 1, 2, 3, 4, 5, 6, 7);
            half8_t bv = __builtin_shufflevector(b0, b1, 0, 1, 2, 3, 4, 5, 6, 7);
            if (ks & 1) acc1 = __builtin_amdgcn_mfma_f32_32x32x16_f16(av, bv, acc1, 0, 0, 0);
            else        acc0 = __builtin_amdgcn_mfma_f32_32x32x16_f16(av, bv, acc0, 0, 0, 0);
        }
        __builtin_amdgcn_s_setprio(0);

        // ---- write-late: stage next chunk into the other buffer ----
        if (c + 1 < NCH) {
            #pragma unroll
            for (int j = 0; j < 4; ++j) {
                int q = tid + j * NTH;
                int a = q >> 5, tq = q & 31;
                if (a < AA) {
                    half4_t h = { (_Float16)stg[j].x, (_Float16)stg[j].y,
                                  (_Float16)stg[j].z, (_Float16)stg[j].w };
                    *(half4_t*)&ampT[tb][a * WSTR + tq * 4] = h;
                }
            }
        }
        phv = nphv;
        BAR();   // syncs ampT only: my reads of [cb] done; my writes to [tb] visible
    }
    // loop's final BAR: all MFMA reads of W tiles complete -> tiles reusable

    // ---- epilogue: each wave dumps its K-half partial into its half of the
    //      (dead) W tile; BAR; kh==0 waves merge, entropy, store ----
    f32x16 acc = acc0 + acc1;
    float* dmp = (float*)((char*)&Wl[wv][0] + kh * 2376);   // [18][33] f32 = 2,376 B
    #pragma unroll
    for (int r = 0; r < 16; ++r) {
        int row = (r & 3) + 8 * (r >> 2) + 4 * mlh;   // HW-verified C/D layout
        if (row < NB) dmp[row * 33 + mrow] = acc[r];
    }
    BAR();

    if (kh == 0 && lane < AA) {
        const float* d0 = (const float*)&Wl[wv][0];
        const float* d1 = (const float*)((char*)&Wl[wv][0] + 2376);
        float v[NB], tot = 0.0f;
        #pragma unroll
        for (int n = 0; n < NB; ++n) {
            v[n] = d0[n * 33 + lane] + d1[n * 33 + lane];
            tot += v[n];
        }
        float inv = 1.0f / (tot + 1e-10f);
        float ne = 0.0f;
        #pragma unroll
        for (int n = 0; n < NB; ++n) {
            float pv = fmaxf(v[n] * inv, 1e-10f);
            ne += pv * logf(pv);
        }
        op[lane] = 1.0f + ne * 0.345975362f;   // 1/log(18)
    }
}

extern "C" void kernel_launch(void* const* d_in, const int* in_sizes, int n_in,
                              void* d_out, int out_size, void* d_ws, size_t ws_size,
                              hipStream_t stream)
{
    const float* phase = (const float*)d_in[0];
    const float* amp   = (const float*)d_in[1];
    float* out = (float*)d_out;
    hipLaunchKernelGGL(mi_fused_kernel, dim3(BB * CC * SS * NPG), dim3(NTH),
                       0, stream, phase, amp, out);
}

// Round 11
// 28.283 us; speedup vs baseline: 1.1488x; 1.0252x over previous
//
#include <hip/hip_runtime.h>
#include <math.h>
#include <stdint.h>

// Problem dims (fixed by reference setup_inputs)
#define BB 4
#define CC 8
#define PP 20
#define AA 30
#define SS 4
#define TT 2048
#define NB 18

#define TC 128                  // t-chunk (K-slab) per iteration
#define NCH (TT / TC)           // 16 chunks
#define PG 2                    // p's per block (both handled by EVERY wave)
#define NPG (PP / PG)           // 10 p-groups
#define WSTR 132                // f16 row stride: 264 B -> b64 pairs bank-step 2 (2-way free)
#define WROWS 19                // rows 0..17 = W, row 18 = dump row for the unwrapped edge
#define NTH 256                 // 4 waves = 4 K-quarters; each does both p's (B-frag reuse)

// Relaxed barrier: LDS-visibility only; global loads stay in flight across it.
#define BAR() do { asm volatile("s_waitcnt lgkmcnt(0)" ::: "memory"); \
                   __builtin_amdgcn_s_barrier(); } while (0)

typedef _Float16 half4_t __attribute__((ext_vector_type(4)));
typedef _Float16 half8_t __attribute__((ext_vector_type(8)));
typedef float f32x16 __attribute__((ext_vector_type(16)));

__device__ __forceinline__ void weight_top2(float x, int& n0, int& n1,
                                            float& w0, float& w1)
{
    const float PI_F  = 3.14159265358979323846f;
    const float INV_H = 2.8647913f;           // 18 / (2*pi)
    float u = (x + PI_F) * INV_H;             // in [0, 18]
    n0 = (int)floorf(u);
    n0 = n0 < 0 ? 0 : (n0 > NB - 1 ? NB - 1 : n0);
    float f  = u - (float)n0 - 0.5f;          // [-0.5, 0.5]
    float af = fabsf(f);
    n1 = n0 + (f >= 0.0f ? 1 : -1);
    float e;
    if (n1 < 0) {                             // reference's unwrapped low edge: w1 ~ 7e-16
        e = 0.0f; n1 = NB;                    // row 18 gets garbage (never extracted)
    } else {
        if (n1 == NB) n1 = 0;                 // positive wrap: same gap formula
        // exp(-(H*(1-2af))*100) = exp(69.81317*af - 34.906585), folded
        e = __expf(fmaf(af, 69.81317008f, -34.90658504f));
    }
    w0 = __builtin_amdgcn_rcpf(1.0f + e);     // rel err ~1e-7 << f16 quantization
    w1 = 1.0f - w0;
}

// ---------------------------------------------------------------------------
// Single fused kernel, B-fragment-reuse waves. Block = (bc, s, pg);
// wave kh owns t-columns [kh*32, kh*32+32) of each chunk and computes BOTH
// p tiles over that K-range: per K-step it reads ONE B-fragment and TWO
// A-fragments (25% fewer LDS fragment reads than one-p-per-wave), issuing
// 2 MFMAs. Scatter/unwrite: lane = (pi=lane>>5, cc=lane&31) -> own column
// of own tile, still strictly wave-local. ampT double-buffer is the only
// shared state -> ONE relaxed barrier per chunk. 20 waves/CU (5 blocks).
// XCD swizzle: the 10 blocks sharing an amp slice map to the SAME XCD.
// ---------------------------------------------------------------------------
__global__ __launch_bounds__(NTH, 5)
void mi_fused_kernel(const float* __restrict__ phase,
                     const float* __restrict__ amp,
                     float* __restrict__ out)
{
    // One arena: [Wl0 | Wl1 | ampT0 | ampT1] = 25,872 B (epilogue dump overlays)
    __shared__ __align__(16) _Float16 lds[2 * WROWS * WSTR + 2 * AA * WSTR];
    _Float16* const Wl0 = lds;
    _Float16* const Wl1 = lds + WROWS * WSTR;
    _Float16* const amp0 = lds + 2 * WROWS * WSTR;

    const int tid = threadIdx.x;
    // ---- XCD-aware swizzle (bijective 1280->1280): sharers of one amp slice
    //      land on one XCD (physical XCD ~ blockIdx%8 round-robin dispatch)
    const int bid = blockIdx.x;
    const int x   = bid & 7;                   // physical XCD
    const int kk  = bid >> 3;                  // 0..159
    const int pg  = kk % NPG;                  // member within amp-sharing group
    const int g   = x + 8 * (kk / NPG);        // 0..127 = bc*SS + s
    const int s   = g & (SS - 1);
    const int bc  = g >> 2;                    // b*CC + c

    const int kh   = tid >> 6;                 // wave = K-quarter (0..3)
    const int lane = tid & 63;
    const int mrow = lane & 31;
    const int mlh  = lane >> 5;
    const int arow = mrow < WROWS ? mrow : (WROWS - 1);  // A rows >=19 -> row 18 (bcast)
    const int brow = mrow < AA    ? mrow : (AA - 1);     // B rows 30,31 -> dup (unused)
    const int col  = kh * 32 + mrow;           // scatter: this lane's owned t-column
    _Float16* const ptile = mlh ? Wl1 : Wl0;   // scatter: this lane's owned p tile

    const float* am  = amp + (size_t)bc * (AA * SS * TT) + (size_t)s * TT;
    // per-lane phase pointer: p = pg*PG + mlh, t-offset = col
    const float* phl = phase + ((size_t)(bc * PP + pg * PG + mlh) * SS + s) * TT + col;

    // ---- prologue: zero both W tiles, stage chunk 0, load phase col ----
    for (int i = tid; i < 627; i += NTH)       // 10,032 B = 627 uint4
        ((uint4*)lds)[i] = make_uint4(0u, 0u, 0u, 0u);
    #pragma unroll
    for (int j = 0; j < 4; ++j) {              // stage chunk 0: 960 quads, coop
        int q = tid + j * NTH;
        int a = q >> 5, tq = q & 31;           // 32 quads per row (TC/4)
        if (a < AA) {
            const float4 v = *(const float4*)&am[(size_t)a * (SS * TT) + tq * 4];
            half4_t h = { (_Float16)v.x, (_Float16)v.y, (_Float16)v.z, (_Float16)v.w };
            *(half4_t*)&amp0[a * WSTR + tq * 4] = h;
        }
    }
    float phv = phl[0];
    BAR();

    f32x16 acc0 = {}, acc1 = {};               // p0 / p1 accumulators
    int pn0 = 0, pn1 = 0;

    for (int c = 0; c < NCH; ++c) {
        const int cb = c & 1, tb = cb ^ 1;
        const _Float16* aB = amp0 + cb * (AA * WSTR);
        _Float16* aW = amp0 + tb * (AA * WSTR);

        // ---- issue next-chunk global loads EARLY (consumed after MFMA) ----
        float nphv = 0.0f;
        float4 stg[4];
        if (c + 1 < NCH) {
            nphv = phl[(c + 1) * TC];
            #pragma unroll
            for (int j = 0; j < 4; ++j) {
                int q = tid + j * NTH;
                int a = q >> 5, tq = q & 31;
                int ac = a < AA ? a : (AA - 1);          // clamp: no OOB read
                stg[j] = *(const float4*)&am[(size_t)ac * (SS * TT) + (c + 1) * TC + tq * 4];
            }
        }

        // ---- unwrite previous chunk's entries, scatter this chunk's ----
        if (c > 0) {
            ptile[pn0 * WSTR + col] = (_Float16)0.0f;
            ptile[pn1 * WSTR + col] = (_Float16)0.0f;
        }
        {
            int n0, n1; float w0, w1;
            weight_top2(phv, n0, n1, w0, w1);
            ptile[n0 * WSTR + col] = (_Float16)w0;
            ptile[n1 * WSTR + col] = (_Float16)w1;
            pn0 = n0; pn1 = n1;
        }

        // ---- 2 K-steps x 2 p: ONE B-frag read feeds both MFMAs ----
        __builtin_amdgcn_s_setprio(1);         // prefer MFMA-phase waves on SIMD
        #pragma unroll
        for (int ks = 0; ks < 2; ++ks) {
            int t0 = kh * 32 + ks * 16 + mlh * 8;
            const _Float16* Bb  = aB  + brow * WSTR + t0;
            const _Float16* A0b = Wl0 + arow * WSTR + t0;
            const _Float16* A1b = Wl1 + arow * WSTR + t0;
            half4_t b0 = *(const half4_t*)Bb;
            half4_t b1 = *(const half4_t*)(Bb + 4);
            half4_t p0a = *(const half4_t*)A0b;
            half4_t p0b = *(const half4_t*)(A0b + 4);
            half4_t p1a = *(const half4_t*)A1b;
            half4_t p1b = *(const half4_t*)(A1b + 4);
            half8_t bv  = __builtin_shufflevector(b0, b1, 0, 1, 2, 3, 4, 5, 6, 7);
            half8_t a0v = __builtin_shufflevector(p0a, p0b, 0, 1, 2, 3, 4, 5, 6, 7);
            half8_t a1v = __builtin_shufflevector(p1a, p1b, 0, 1, 2, 3, 4, 5, 6, 7);
            acc0 = __builtin_amdgcn_mfma_f32_32x32x16_f16(a0v, bv, acc0, 0, 0, 0);
            acc1 = __builtin_amdgcn_mfma_f32_32x32x16_f16(a1v, bv, acc1, 0, 0, 0);
        }
        __builtin_amdgcn_s_setprio(0);

        // ---- write-late: stage next chunk into the other buffer ----
        if (c + 1 < NCH) {
            #pragma unroll
            for (int j = 0; j < 4; ++j) {
                int q = tid + j * NTH;
                int a = q >> 5, tq = q & 31;
                if (a < AA) {
                    half4_t h = { (_Float16)stg[j].x, (_Float16)stg[j].y,
                                  (_Float16)stg[j].z, (_Float16)stg[j].w };
                    *(half4_t*)&aW[a * WSTR + tq * 4] = h;
                }
            }
        }
        phv = nphv;
        BAR();   // syncs ampT only: my reads of [cb] done; my writes to [tb] visible
    }
    // loop's final BAR: all MFMA reads of W/ampT complete -> arena reusable

    // ---- epilogue: dump [kh][pi][18][32] f32 partials over the arena ----
    float* const df = (float*)lds;             // 8 x 576 f32 = 18,432 B < 25,872 B
    #pragma unroll
    for (int r = 0; r < 16; ++r) {
        int row = (r & 3) + 8 * (r >> 2) + 4 * mlh;   // HW-verified C/D layout
        if (row < NB) {
            df[(kh * 2 + 0) * 576 + row * 32 + mrow] = acc0[r];
            df[(kh * 2 + 1) * 576 + row * 32 + mrow] = acc1[r];
        }
    }
    BAR();

    // waves 0,1: reduce 4 kh-partials for p = pg*PG + kh, entropy, store
    if (kh < PG && lane < AA) {
        float v[NB], tot = 0.0f;
        #pragma unroll
        for (int n = 0; n < NB; ++n) {
            v[n] = df[(0 * 2 + kh) * 576 + n * 32 + lane]
                 + df[(1 * 2 + kh) * 576 + n * 32 + lane]
                 + df[(2 * 2 + kh) * 576 + n * 32 + lane]
                 + df[(3 * 2 + kh) * 576 + n * 32 + lane];
            tot += v[n];
        }
        float inv = 1.0f / (tot + 1e-10f);
        float ne = 0.0f;
        #pragma unroll
        for (int n = 0; n < NB; ++n) {
            float pv = fmaxf(v[n] * inv, 1e-10f);
            ne += pv * logf(pv);
        }
        out[((size_t)(bc * SS + s) * PP + pg * PG + kh) * AA + lane] =
            1.0f + ne * 0.345975362f;          // 1/log(18)
    }
}

extern "C" void kernel_launch(void* const* d_in, const int* in_sizes, int n_in,
                              void* d_out, int out_size, void* d_ws, size_t ws_size,
                              hipStream_t stream)
{
    const float* phase = (const float*)d_in[0];
    const float* amp   = (const float*)d_in[1];
    float* out = (float*)d_out;
    hipLaunchKernelGGL(mi_fused_kernel, dim3(BB * CC * SS * NPG), dim3(NTH),
                       0, stream, phase, amp, out);
}